// Round 8
// baseline (216.433 us; speedup 1.0000x reference)
//
#include <hip/hip_runtime.h>
#include <math.h>

// GPT attention block: B=8, T=1024, E=768, H=12, D=64. fp32 in/out.
// Round 8: GEMM grid/tile re-shape for zero dispatch tail.
//  - QKV GEMM: 128x192 tiles -> grid 12x64 = 768 blocks = 256 CU x 3 resident
//    (was 1152 blocks over 768 slots = 1.5 rounds, 75% utilization)
//  - proj GEMM: 64x128 tiles -> 768 blocks (was 384 = 1-2/CU)
//  - GEMM templated on (BM,BN,wave arrangement); band swizzle kept
// Flash + prep unchanged from round 7.

#define B_ 8
#define T_ 1024
#define E_ 768
#define H_ 12
#define D_ 64
#define E3 (3 * E_)

typedef __attribute__((ext_vector_type(8))) short bf16x8;
typedef __attribute__((ext_vector_type(4))) float f32x4;

#define SCALE 0.18033688f // 0.125 * log2(e)

__device__ __forceinline__ unsigned short f2bf(float f) {
    unsigned int u = __builtin_bit_cast(unsigned int, f);
    u += 0x7fffu + ((u >> 16) & 1u);   // RNE
    return (unsigned short)(u >> 16);
}

__device__ __forceinline__ void async_copy16(void* lds, const void* g) {
    __builtin_amdgcn_global_load_lds(
        (const __attribute__((address_space(1))) void*)g,
        (__attribute__((address_space(3))) void*)lds, 16, 0, 0);
}

// ---------------- fused prep: x->bf16, w_attn^T, w_proj^T ----------------
#define NCVT 6144                 // (8192*768/4)/256
#define NTA  (72 * 24)            // (E3/32) x (E_/32)
#define NTP  (24 * 24)            // (E_/32) x (E_/32)

__device__ __forceinline__ void transpose_tile(
    const float* __restrict__ W, unsigned short* __restrict__ Wt,
    int K, int N, int gx, int gy, unsigned short (*tile)[33])
{
    const int n0 = gx * 32, k0 = gy * 32;
    const int tx = threadIdx.x & 31, ty = threadIdx.x >> 5;
    #pragma unroll
    for (int i = 0; i < 4; ++i)
        tile[ty + i * 8][tx] = f2bf(W[(size_t)(k0 + ty + i * 8) * N + n0 + tx]);
    __syncthreads();
    #pragma unroll
    for (int i = 0; i < 4; ++i)
        Wt[(size_t)(n0 + ty + i * 8) * K + k0 + tx] = tile[tx][ty + i * 8];
}

__global__ __launch_bounds__(256) void prep_kernel(
    const float* __restrict__ x, unsigned short* __restrict__ x_bf,
    const float* __restrict__ w_attn, unsigned short* __restrict__ wat,
    const float* __restrict__ w_proj, unsigned short* __restrict__ wpt)
{
    __shared__ unsigned short tile[32][33];
    const int bid = blockIdx.x;
    if (bid < NCVT) {
        const int i = bid * 256 + threadIdx.x;
        float4 f = ((const float4*)x)[i];
        ushort4 o;
        o.x = f2bf(f.x); o.y = f2bf(f.y); o.z = f2bf(f.z); o.w = f2bf(f.w);
        ((ushort4*)x_bf)[i] = o;
    } else if (bid < NCVT + NTA) {
        const int t = bid - NCVT;
        transpose_tile(w_attn, wat, E_, E3, t % 72, t / 72, tile);
    } else {
        const int t = bid - NCVT - NTA;
        transpose_tile(w_proj, wpt, E_, E_, t % 24, t / 24, tile);
    }
}

// ---------------- bf16 MFMA GEMM ----------------
// C[M,N] = A[M,K] @ Wt[N,K]^T + bias. BM x BN tile, BK=64, 4 waves (WR x WC).
// MODE 0: plain. MODE 1 (BM=128,BN=192): q cols (bx<4) scaled by SCALE; V cols
// (bx>=8) written transposed to vt[(b*H+h)*64+d][t]; K cols written normally.
// Band swizzle: 8 row-blocks x all col-blocks per band for L2 reuse.
template <typename OutT, int MODE, int BM, int BN, int WR, int WC>
__global__ __launch_bounds__(256) void gemm_mfma_kernel(
    const unsigned short* __restrict__ A,   // [M,K] bf16
    const unsigned short* __restrict__ Wt,  // [N,K] bf16
    const float* __restrict__ bias,
    OutT* __restrict__ C,
    unsigned short* __restrict__ vt,        // MODE 1 only
    int M, int N, int K)
{
    constexpr int MT = BM / WR / 16;   // 16-tiles per wave, m
    constexpr int NT = BN / WC / 16;   // 16-tiles per wave, n
    constexpr int CA = BM / 32;        // A staging chunks per wave
    constexpr int CB = BN / 32;        // B staging chunks per wave

    __shared__ unsigned short Abuf[BM * 64];
    __shared__ unsigned short Bbuf[BN * 64];

    const int tid = threadIdx.x;
    const int lane = tid & 63;
    const int w = tid >> 6;
    const int n16 = lane & 15;
    const int quad = lane >> 4;

    // band swizzle (gridDim.y is a multiple of 8)
    const int nbx = gridDim.x;
    const int lin = blockIdx.y * nbx + blockIdx.x;
    const int band_sz = 8 * nbx;
    const int band = lin / band_sz;
    const int rr = lin % band_sz;
    const int bm = (band * 8 + (rr & 7)) * BM;
    const int bx = rr >> 3;                 // swizzled block col index
    const int bn = bx * BN;

    const int wmbase = (w / WC) * (BM / WR);
    const int wnbase = (w % WC) * (BN / WC);

    const int lrow = lane >> 3;
    const int lcol = ((lane & 7) ^ lrow) * 8;

    f32x4 acc[MT][NT] = {};

    for (int k0 = 0; k0 < K; k0 += 64) {
        __syncthreads();
        #pragma unroll
        for (int i = 0; i < CA; ++i) {
            const int c = w * CA + i;
            const int row = c * 8 + lrow;
            async_copy16(&Abuf[c * 512], A + (size_t)(bm + row) * K + k0 + lcol);
        }
        #pragma unroll
        for (int i = 0; i < CB; ++i) {
            const int c = w * CB + i;
            const int row = c * 8 + lrow;
            async_copy16(&Bbuf[c * 512], Wt + (size_t)(bn + row) * K + k0 + lcol);
        }
        __syncthreads();

        #pragma unroll
        for (int kc = 0; kc < 2; ++kc) {
            bf16x8 af[MT], bf[NT];
            #pragma unroll
            for (int mt = 0; mt < MT; ++mt) {
                const int r = wmbase + mt * 16 + n16;
                af[mt] = *(const bf16x8*)&Abuf[r * 64 + ((kc * 4 + quad) ^ (r & 7)) * 8];
            }
            #pragma unroll
            for (int nt = 0; nt < NT; ++nt) {
                const int r = wnbase + nt * 16 + n16;
                bf[nt] = *(const bf16x8*)&Bbuf[r * 64 + ((kc * 4 + quad) ^ (r & 7)) * 8];
            }
            #pragma unroll
            for (int mt = 0; mt < MT; ++mt)
                #pragma unroll
                for (int nt = 0; nt < NT; ++nt)
                    acc[mt][nt] = __builtin_amdgcn_mfma_f32_16x16x32_bf16(
                        af[mt], bf[nt], acc[mt][nt], 0, 0, 0);
        }
    }

    if (MODE == 1 && bx >= 8) {
        // V region: cols 1536..2303 -> vt[(b*768) + (col-1536)][token&1023]
        #pragma unroll
        for (int mt = 0; mt < MT; ++mt) {
            const int tt = bm + wmbase + mt * 16 + quad * 4;   // base token
            const size_t bb = (size_t)(tt >> 10) * 768;
            const int tin = tt & 1023;
            #pragma unroll
            for (int nt = 0; nt < NT; ++nt) {
                const int col = bn + wnbase + nt * 16 + n16;
                const int ch = col - 1536;
                const float bv = bias[col];
                ushort4 o4;
                o4.x = f2bf(acc[mt][nt][0] + bv);
                o4.y = f2bf(acc[mt][nt][1] + bv);
                o4.z = f2bf(acc[mt][nt][2] + bv);
                o4.w = f2bf(acc[mt][nt][3] + bv);
                *(ushort4*)&vt[(bb + ch) * 1024 + tin] = o4;
            }
        }
        return;
    }

    const bool scale_q = (MODE == 1) && (bx < 4);
    #pragma unroll
    for (int mt = 0; mt < MT; ++mt) {
        #pragma unroll
        for (int r = 0; r < 4; ++r) {
            const size_t rowoff = (size_t)(bm + wmbase + mt * 16 + quad * 4 + r) * N;
            #pragma unroll
            for (int nt = 0; nt < NT; ++nt) {
                const int col = bn + wnbase + nt * 16 + n16;
                float v = acc[mt][nt][r] + bias[col];
                if (scale_q) v *= SCALE;
                if constexpr (sizeof(OutT) == 2) C[rowoff + col] = (OutT)f2bf(v);
                else                             C[rowoff + col] = (OutT)v;
            }
        }
    }
}

// ---------------- Flash attention (unchanged from round 6) ----------------
#define BKEY 128
#define VSTR 136

__global__ __launch_bounds__(256) void flash_attn_kernel(
    const unsigned short* __restrict__ qkv,
    const unsigned short* __restrict__ vt,   // [(b*H+h)*64+d][1024] bf16
    unsigned short* __restrict__ out)
{
    __shared__ unsigned short Ks[BKEY * 64];
    __shared__ unsigned short Vts[64 * BKEY];
    __shared__ unsigned short Ps[4 * 16 * VSTR];

    const int tid = threadIdx.x;
    const int idx = blockIdx.x;
    const int head = idx % 96;
    const int p    = idx / 96;
    const int h = head % H_;
    const int b = head / H_;

    const int lane = tid & 63;
    const int w    = tid >> 6;
    const int n16  = lane & 15;
    const int quad = lane >> 4;

    const size_t base = (size_t)b * T_ * E3;
    const unsigned short* qbase = qkv + base + h * D_;          // pre-scaled q
    const unsigned short* kbase = qkv + base + E_ + h * D_;
    const unsigned short* vtb   = vt + (size_t)(b * H_ + h) * 64 * 1024;

    const int lrow = lane >> 3;
    const int lcol = ((lane & 7) ^ lrow) * 8;
    const int vr4 = lane >> 4;
    const int vc  = lane & 15;

    unsigned short* pw = &Ps[w * 16 * VSTR];

    #pragma unroll
    for (int half = 0; half < 2; ++half) {
        const int qt = half ? (15 - p) : p;
        const int q0 = qt * 64;
        const int nIter = (qt + 2) >> 1;
        const int wave_q_min = q0 + w * 16;
        const int wave_last  = wave_q_min + 15;
        const int qrow_base  = wave_q_min + quad * 4;

        const unsigned short* qrp = qbase + (size_t)(wave_q_min + n16) * E3 + quad * 8;
        bf16x8 qf0 = *(const bf16x8*)qrp;
        bf16x8 qf1 = *(const bf16x8*)(qrp + 32);

        f32x4 o[4] = {};
        float lsum[4] = {};

        for (int it = 0; it < nIter; ++it) {
            const int k0 = it * BKEY;
            __syncthreads();

            #pragma unroll
            for (int i = 0; i < 4; ++i) {
                const int c = w * 4 + i;
                const int row = c * 8 + lrow;
                async_copy16(&Ks[c * 512], kbase + (size_t)(k0 + row) * E3 + lcol);
            }
            #pragma unroll
            for (int i = 0; i < 4; ++i) {
                const int j = w * 4 + i;
                const int row = 4 * j + vr4;
                async_copy16(&Vts[4 * j * BKEY],
                             vtb + (size_t)row * 1024 + k0 + ((vc ^ (row & 15)) * 8));
            }
            __syncthreads();

            int knt_lim = ((wave_last - k0) >> 4) + 1;
            if (knt_lim > 8) knt_lim = 8;
            const int ks_lim = (knt_lim + 1) >> 1;
            int Ab = wave_q_min - k0 - 15;
            int kfull = Ab < 0 ? 0 : (Ab >> 4) + 1;
            if (kfull > 8) kfull = 8;

            f32x4 s[8];
            #pragma unroll
            for (int knt = 0; knt < 8; ++knt) {
                if (knt < knt_lim) {
                    const int r = knt * 16 + n16;
                    bf16x8 kf0 = *(const bf16x8*)&Ks[r * 64 + ((0 + quad) ^ (r & 7)) * 8];
                    bf16x8 kf1 = *(const bf16x8*)&Ks[r * 64 + ((4 + quad) ^ (r & 7)) * 8];
                    f32x4 acc = {0.f, 0.f, 0.f, 0.f};
                    acc = __builtin_amdgcn_mfma_f32_16x16x32_bf16(qf0, kf0, acc, 0, 0, 0);
                    acc = __builtin_amdgcn_mfma_f32_16x16x32_bf16(qf1, kf1, acc, 0, 0, 0);
                    s[knt] = acc;
                }
            }
            #pragma unroll
            for (int knt = 0; knt < 8; ++knt) {
                if (knt >= kfull) {
                    const int kcol = k0 + knt * 16 + n16;
                    #pragma unroll
                    for (int r = 0; r < 4; ++r) {
                        float v = (knt < knt_lim) ? s[knt][r] : -1e30f;
                        if (kcol > qrow_base + r) v = -1e30f;
                        s[knt][r] = v;
                    }
                }
            }

            #pragma unroll
            for (int knt = 0; knt < 8; ++knt)
                #pragma unroll
                for (int r = 0; r < 4; ++r) {
                    float pv = __builtin_amdgcn_exp2f(s[knt][r]);
                    lsum[r] += pv;
                    unsigned int u = __builtin_bit_cast(unsigned int, pv);
                    pw[(quad * 4 + r) * VSTR + knt * 16 + n16] =
                        (unsigned short)((u + 0x8000u) >> 16);
                }

            #pragma unroll
            for (int ks = 0; ks < 4; ++ks) {
                if (ks < ks_lim) {
                    bf16x8 pf = *(const bf16x8*)&pw[n16 * VSTR + ks * 32 + quad * 8];
                    #pragma unroll
                    for (int dt = 0; dt < 4; ++dt) {
                        const int row = dt * 16 + n16;
                        bf16x8 vf = *(const bf16x8*)&Vts[row * BKEY +
                                        (((ks * 4 + quad) ^ n16) * 8)];
                        o[dt] = __builtin_amdgcn_mfma_f32_16x16x32_bf16(pf, vf, o[dt], 0, 0, 0);
                    }
                }
            }
        }

        #pragma unroll
        for (int off = 1; off <= 8; off <<= 1)
            #pragma unroll
            for (int r = 0; r < 4; ++r)
                lsum[r] += __shfl_xor(lsum[r], off);

        #pragma unroll
        for (int r = 0; r < 4; ++r) {
            const float inv = 1.f / lsum[r];
            unsigned short* orow = out + ((size_t)b * T_ + qrow_base + r) * E_ + h * D_;
            #pragma unroll
            for (int dt = 0; dt < 4; ++dt)
                orow[dt * 16 + n16] = f2bf(o[dt][r] * inv);
        }
    }
}

extern "C" void kernel_launch(void* const* d_in, const int* in_sizes, int n_in,
                              void* d_out, int out_size, void* d_ws, size_t ws_size,
                              hipStream_t stream)
{
    const float* x      = (const float*)d_in[0];
    const float* w_attn = (const float*)d_in[1];
    const float* b_attn = (const float*)d_in[2];
    const float* w_proj = (const float*)d_in[3];
    const float* b_proj = (const float*)d_in[4];
    float* out = (float*)d_out;

    const int M = B_ * T_;  // 8192

    unsigned short* x_bf   = (unsigned short*)d_ws;           // [M,E]
    unsigned short* wat    = x_bf + (size_t)M * E_;           // [3E,E]
    unsigned short* wpt    = wat + (size_t)E3 * E_;           // [E,E]
    unsigned short* qkv_bf = wpt + (size_t)E_ * E_;           // [M,3E] (V region unused)
    unsigned short* att_bf = qkv_bf + (size_t)M * E3;         // [M,E]
    unsigned short* vt_bf  = att_bf + (size_t)M * E_;         // [B*H*64,1024]

    prep_kernel<<<NCVT + NTA + NTP, 256, 0, stream>>>(x, x_bf, w_attn, wat, w_proj, wpt);

    // QKV: 128x192 tiles -> 12 x 64 = 768 blocks (one full round, 3/CU)
    gemm_mfma_kernel<unsigned short, 1, 128, 192, 2, 2>
        <<<dim3(E3 / 192, M / 128), 256, 0, stream>>>(
        x_bf, wat, b_attn, qkv_bf, vt_bf, M, E3, E_);

    flash_attn_kernel<<<B_ * H_ * 8, 256, 0, stream>>>(qkv_bf, vt_bf, att_bf);

    // proj: 64x128 tiles -> 6 x 128 = 768 blocks
    gemm_mfma_kernel<float, 0, 64, 128, 2, 2>
        <<<dim3(E_ / 128, M / 64), 256, 0, stream>>>(
        att_bf, wpt, b_proj, out, nullptr, M, E_, E_);
}

// Round 9
// 201.361 us; speedup vs baseline: 1.0749x; 1.0749x over previous
//
#include <hip/hip_runtime.h>
#include <math.h>

// GPT attention block: B=8, T=1024, E=768, H=12, D=64. fp32 in/out.
// Round 9:
//  - QKV GEMM reverted to 128x128 (round-7 measured best: 57.6us; round-8's
//    128x192 cost occupancy, -12us regression)
//  - proj stays 64x128 (768 blocks, small win)
//  - flash: paired q-tiles (p, 15-p) merged into ONE K-loop sharing staged
//    K/V tiles -> staging/barrier iters 9 -> avg 6.5 per block
// prep unchanged.

#define B_ 8
#define T_ 1024
#define E_ 768
#define H_ 12
#define D_ 64
#define E3 (3 * E_)

typedef __attribute__((ext_vector_type(8))) short bf16x8;
typedef __attribute__((ext_vector_type(4))) float f32x4;

#define SCALE 0.18033688f // 0.125 * log2(e)

__device__ __forceinline__ unsigned short f2bf(float f) {
    unsigned int u = __builtin_bit_cast(unsigned int, f);
    u += 0x7fffu + ((u >> 16) & 1u);   // RNE
    return (unsigned short)(u >> 16);
}

__device__ __forceinline__ void async_copy16(void* lds, const void* g) {
    __builtin_amdgcn_global_load_lds(
        (const __attribute__((address_space(1))) void*)g,
        (__attribute__((address_space(3))) void*)lds, 16, 0, 0);
}

// ---------------- fused prep: x->bf16, w_attn^T, w_proj^T ----------------
#define NCVT 6144                 // (8192*768/4)/256
#define NTA  (72 * 24)            // (E3/32) x (E_/32)
#define NTP  (24 * 24)            // (E_/32) x (E_/32)

__device__ __forceinline__ void transpose_tile(
    const float* __restrict__ W, unsigned short* __restrict__ Wt,
    int K, int N, int gx, int gy, unsigned short (*tile)[33])
{
    const int n0 = gx * 32, k0 = gy * 32;
    const int tx = threadIdx.x & 31, ty = threadIdx.x >> 5;
    #pragma unroll
    for (int i = 0; i < 4; ++i)
        tile[ty + i * 8][tx] = f2bf(W[(size_t)(k0 + ty + i * 8) * N + n0 + tx]);
    __syncthreads();
    #pragma unroll
    for (int i = 0; i < 4; ++i)
        Wt[(size_t)(n0 + ty + i * 8) * K + k0 + tx] = tile[tx][ty + i * 8];
}

__global__ __launch_bounds__(256) void prep_kernel(
    const float* __restrict__ x, unsigned short* __restrict__ x_bf,
    const float* __restrict__ w_attn, unsigned short* __restrict__ wat,
    const float* __restrict__ w_proj, unsigned short* __restrict__ wpt)
{
    __shared__ unsigned short tile[32][33];
    const int bid = blockIdx.x;
    if (bid < NCVT) {
        const int i = bid * 256 + threadIdx.x;
        float4 f = ((const float4*)x)[i];
        ushort4 o;
        o.x = f2bf(f.x); o.y = f2bf(f.y); o.z = f2bf(f.z); o.w = f2bf(f.w);
        ((ushort4*)x_bf)[i] = o;
    } else if (bid < NCVT + NTA) {
        const int t = bid - NCVT;
        transpose_tile(w_attn, wat, E_, E3, t % 72, t / 72, tile);
    } else {
        const int t = bid - NCVT - NTA;
        transpose_tile(w_proj, wpt, E_, E_, t % 24, t / 24, tile);
    }
}

// ---------------- bf16 MFMA GEMM ----------------
// C[M,N] = A[M,K] @ Wt[N,K]^T + bias. BM x BN tile, BK=64, 4 waves (WR x WC).
// MODE 0: plain. MODE 1: q cols (col<768) scaled by SCALE; V cols (col>=1536)
// written transposed to vt[(b*H+h)*64+d][t]; K cols written normally.
template <typename OutT, int MODE, int BM, int BN, int WR, int WC>
__global__ __launch_bounds__(256) void gemm_mfma_kernel(
    const unsigned short* __restrict__ A,   // [M,K] bf16
    const unsigned short* __restrict__ Wt,  // [N,K] bf16
    const float* __restrict__ bias,
    OutT* __restrict__ C,
    unsigned short* __restrict__ vt,        // MODE 1 only
    int M, int N, int K)
{
    constexpr int MT = BM / WR / 16;
    constexpr int NT = BN / WC / 16;
    constexpr int CA = BM / 32;
    constexpr int CB = BN / 32;
    constexpr int QBX = 768 / BN;    // first block-col past q region
    constexpr int VBX = 1536 / BN;   // first block-col of V region

    __shared__ unsigned short Abuf[BM * 64];
    __shared__ unsigned short Bbuf[BN * 64];

    const int tid = threadIdx.x;
    const int lane = tid & 63;
    const int w = tid >> 6;
    const int n16 = lane & 15;
    const int quad = lane >> 4;

    // band swizzle (gridDim.y is a multiple of 8)
    const int nbx = gridDim.x;
    const int lin = blockIdx.y * nbx + blockIdx.x;
    const int band_sz = 8 * nbx;
    const int band = lin / band_sz;
    const int rr = lin % band_sz;
    const int bm = (band * 8 + (rr & 7)) * BM;
    const int bx = rr >> 3;
    const int bn = bx * BN;

    const int wmbase = (w / WC) * (BM / WR);
    const int wnbase = (w % WC) * (BN / WC);

    const int lrow = lane >> 3;
    const int lcol = ((lane & 7) ^ lrow) * 8;

    f32x4 acc[MT][NT] = {};

    for (int k0 = 0; k0 < K; k0 += 64) {
        __syncthreads();
        #pragma unroll
        for (int i = 0; i < CA; ++i) {
            const int c = w * CA + i;
            const int row = c * 8 + lrow;
            async_copy16(&Abuf[c * 512], A + (size_t)(bm + row) * K + k0 + lcol);
        }
        #pragma unroll
        for (int i = 0; i < CB; ++i) {
            const int c = w * CB + i;
            const int row = c * 8 + lrow;
            async_copy16(&Bbuf[c * 512], Wt + (size_t)(bn + row) * K + k0 + lcol);
        }
        __syncthreads();

        #pragma unroll
        for (int kc = 0; kc < 2; ++kc) {
            bf16x8 af[MT], bf[NT];
            #pragma unroll
            for (int mt = 0; mt < MT; ++mt) {
                const int r = wmbase + mt * 16 + n16;
                af[mt] = *(const bf16x8*)&Abuf[r * 64 + ((kc * 4 + quad) ^ (r & 7)) * 8];
            }
            #pragma unroll
            for (int nt = 0; nt < NT; ++nt) {
                const int r = wnbase + nt * 16 + n16;
                bf[nt] = *(const bf16x8*)&Bbuf[r * 64 + ((kc * 4 + quad) ^ (r & 7)) * 8];
            }
            #pragma unroll
            for (int mt = 0; mt < MT; ++mt)
                #pragma unroll
                for (int nt = 0; nt < NT; ++nt)
                    acc[mt][nt] = __builtin_amdgcn_mfma_f32_16x16x32_bf16(
                        af[mt], bf[nt], acc[mt][nt], 0, 0, 0);
        }
    }

    if (MODE == 1 && bx >= VBX) {
        #pragma unroll
        for (int mt = 0; mt < MT; ++mt) {
            const int tt = bm + wmbase + mt * 16 + quad * 4;
            const size_t bb = (size_t)(tt >> 10) * 768;
            const int tin = tt & 1023;
            #pragma unroll
            for (int nt = 0; nt < NT; ++nt) {
                const int col = bn + wnbase + nt * 16 + n16;
                const int ch = col - 1536;
                const float bv = bias[col];
                ushort4 o4;
                o4.x = f2bf(acc[mt][nt][0] + bv);
                o4.y = f2bf(acc[mt][nt][1] + bv);
                o4.z = f2bf(acc[mt][nt][2] + bv);
                o4.w = f2bf(acc[mt][nt][3] + bv);
                *(ushort4*)&vt[(bb + ch) * 1024 + tin] = o4;
            }
        }
        return;
    }

    const bool scale_q = (MODE == 1) && (bx < QBX);
    #pragma unroll
    for (int mt = 0; mt < MT; ++mt) {
        #pragma unroll
        for (int r = 0; r < 4; ++r) {
            const size_t rowoff = (size_t)(bm + wmbase + mt * 16 + quad * 4 + r) * N;
            #pragma unroll
            for (int nt = 0; nt < NT; ++nt) {
                const int col = bn + wnbase + nt * 16 + n16;
                float v = acc[mt][nt][r] + bias[col];
                if (scale_q) v *= SCALE;
                if constexpr (sizeof(OutT) == 2) C[rowoff + col] = (OutT)f2bf(v);
                else                             C[rowoff + col] = (OutT)v;
            }
        }
    }
}

// ---------------- Flash attention v4: merged paired q-tiles ----------------
// Block = (b, h, p): q-tiles A=p and B=15-p share one K-loop. Tile A consumes
// only the first nIterA staged tiles; staging runs nIterB times (8..5) instead
// of 9. Compute phases total 9 per block (balanced).
#define BKEY 128
#define VSTR 136

__global__ __launch_bounds__(256) void flash_attn_kernel(
    const unsigned short* __restrict__ qkv,
    const unsigned short* __restrict__ vt,   // [(b*H+h)*64+d][1024] bf16
    unsigned short* __restrict__ out)
{
    __shared__ unsigned short Ks[BKEY * 64];
    __shared__ unsigned short Vts[64 * BKEY];
    __shared__ unsigned short Ps[4 * 16 * VSTR];

    const int tid = threadIdx.x;
    const int idx = blockIdx.x;
    const int head = idx % 96;
    const int p    = idx / 96;          // 0..7
    const int h = head % H_;
    const int b = head / H_;

    const int lane = tid & 63;
    const int w    = tid >> 6;
    const int n16  = lane & 15;
    const int quad = lane >> 4;

    const size_t base = (size_t)b * T_ * E3;
    const unsigned short* qbase = qkv + base + h * D_;          // pre-scaled q
    const unsigned short* kbase = qkv + base + E_ + h * D_;
    const unsigned short* vtb   = vt + (size_t)(b * H_ + h) * 64 * 1024;

    const int lrow = lane >> 3;
    const int lcol = ((lane & 7) ^ lrow) * 8;
    const int vr4 = lane >> 4;
    const int vc  = lane & 15;

    unsigned short* pw = &Ps[w * 16 * VSTR];

    const int qtA = p, qtB = 15 - p;
    const int nIterA = (qtA + 2) >> 1;
    const int nIterB = (qtB + 2) >> 1;
    const int wqA = qtA * 64 + w * 16;
    const int wqB = qtB * 64 + w * 16;
    const int qrA = wqA + quad * 4;
    const int qrB = wqB + quad * 4;

    const unsigned short* qrpA = qbase + (size_t)(wqA + n16) * E3 + quad * 8;
    bf16x8 qfA0 = *(const bf16x8*)qrpA;
    bf16x8 qfA1 = *(const bf16x8*)(qrpA + 32);
    const unsigned short* qrpB = qbase + (size_t)(wqB + n16) * E3 + quad * 8;
    bf16x8 qfB0 = *(const bf16x8*)qrpB;
    bf16x8 qfB1 = *(const bf16x8*)(qrpB + 32);

    f32x4 oA[4] = {}, oB[4] = {};
    float lsA[4] = {}, lsB[4] = {};

    for (int it = 0; it < nIterB; ++it) {
        const int k0 = it * BKEY;
        __syncthreads();

        // ---- stage K [key][dim], XOR-swizzled, async ----
        #pragma unroll
        for (int i = 0; i < 4; ++i) {
            const int c = w * 4 + i;
            const int row = c * 8 + lrow;
            async_copy16(&Ks[c * 512], kbase + (size_t)(k0 + row) * E3 + lcol);
        }
        // ---- stage V^T [dim][key] from vt, XOR key-group swizzle, async ----
        #pragma unroll
        for (int i = 0; i < 4; ++i) {
            const int j = w * 4 + i;
            const int row = 4 * j + vr4;
            async_copy16(&Vts[4 * j * BKEY],
                         vtb + (size_t)row * 1024 + k0 + ((vc ^ (row & 15)) * 8));
        }
        __syncthreads();

        auto phase = [&](bf16x8 qf0, bf16x8 qf1, f32x4* o, float* lsum,
                         int wave_q_min, int qrow_base) {
            int knt_lim = ((wave_q_min + 15 - k0) >> 4) + 1;
            if (knt_lim > 8) knt_lim = 8;
            const int ks_lim = (knt_lim + 1) >> 1;
            int Ab2 = wave_q_min - k0 - 15;
            int kfull = Ab2 < 0 ? 0 : (Ab2 >> 4) + 1;
            if (kfull > 8) kfull = 8;

            f32x4 s[8];
            #pragma unroll
            for (int knt = 0; knt < 8; ++knt) {
                if (knt < knt_lim) {
                    const int r = knt * 16 + n16;
                    bf16x8 kf0 = *(const bf16x8*)&Ks[r * 64 + ((0 + quad) ^ (r & 7)) * 8];
                    bf16x8 kf1 = *(const bf16x8*)&Ks[r * 64 + ((4 + quad) ^ (r & 7)) * 8];
                    f32x4 acc = {0.f, 0.f, 0.f, 0.f};
                    acc = __builtin_amdgcn_mfma_f32_16x16x32_bf16(qf0, kf0, acc, 0, 0, 0);
                    acc = __builtin_amdgcn_mfma_f32_16x16x32_bf16(qf1, kf1, acc, 0, 0, 0);
                    s[knt] = acc;
                }
            }
            #pragma unroll
            for (int knt = 0; knt < 8; ++knt) {
                if (knt >= kfull) {
                    const int kcol = k0 + knt * 16 + n16;
                    #pragma unroll
                    for (int r = 0; r < 4; ++r) {
                        float v = (knt < knt_lim) ? s[knt][r] : -1e30f;
                        if (kcol > qrow_base + r) v = -1e30f;
                        s[knt][r] = v;
                    }
                }
            }

            #pragma unroll
            for (int knt = 0; knt < 8; ++knt)
                #pragma unroll
                for (int r = 0; r < 4; ++r) {
                    float pv = __builtin_amdgcn_exp2f(s[knt][r]);
                    lsum[r] += pv;
                    unsigned int u = __builtin_bit_cast(unsigned int, pv);
                    pw[(quad * 4 + r) * VSTR + knt * 16 + n16] =
                        (unsigned short)((u + 0x8000u) >> 16);
                }

            #pragma unroll
            for (int ks = 0; ks < 4; ++ks) {
                if (ks < ks_lim) {
                    bf16x8 pf = *(const bf16x8*)&pw[n16 * VSTR + ks * 32 + quad * 8];
                    #pragma unroll
                    for (int dt = 0; dt < 4; ++dt) {
                        const int row = dt * 16 + n16;
                        bf16x8 vf = *(const bf16x8*)&Vts[row * BKEY +
                                        (((ks * 4 + quad) ^ n16) * 8)];
                        o[dt] = __builtin_amdgcn_mfma_f32_16x16x32_bf16(pf, vf, o[dt], 0, 0, 0);
                    }
                }
            }
        };

        phase(qfB0, qfB1, oB, lsB, wqB, qrB);
        if (it < nIterA) phase(qfA0, qfA1, oA, lsA, wqA, qrA);
    }

    // ---- final l reductions + epilogues ----
    #pragma unroll
    for (int off = 1; off <= 8; off <<= 1)
        #pragma unroll
        for (int r = 0; r < 4; ++r) {
            lsA[r] += __shfl_xor(lsA[r], off);
            lsB[r] += __shfl_xor(lsB[r], off);
        }

    #pragma unroll
    for (int r = 0; r < 4; ++r) {
        const float invA = 1.f / lsA[r];
        unsigned short* orowA = out + ((size_t)b * T_ + qrA + r) * E_ + h * D_;
        #pragma unroll
        for (int dt = 0; dt < 4; ++dt)
            orowA[dt * 16 + n16] = f2bf(oA[dt][r] * invA);
        const float invB = 1.f / lsB[r];
        unsigned short* orowB = out + ((size_t)b * T_ + qrB + r) * E_ + h * D_;
        #pragma unroll
        for (int dt = 0; dt < 4; ++dt)
            orowB[dt * 16 + n16] = f2bf(oB[dt][r] * invB);
    }
}

extern "C" void kernel_launch(void* const* d_in, const int* in_sizes, int n_in,
                              void* d_out, int out_size, void* d_ws, size_t ws_size,
                              hipStream_t stream)
{
    const float* x      = (const float*)d_in[0];
    const float* w_attn = (const float*)d_in[1];
    const float* b_attn = (const float*)d_in[2];
    const float* w_proj = (const float*)d_in[3];
    const float* b_proj = (const float*)d_in[4];
    float* out = (float*)d_out;

    const int M = B_ * T_;  // 8192

    unsigned short* x_bf   = (unsigned short*)d_ws;           // [M,E]
    unsigned short* wat    = x_bf + (size_t)M * E_;           // [3E,E]
    unsigned short* wpt    = wat + (size_t)E3 * E_;           // [E,E]
    unsigned short* qkv_bf = wpt + (size_t)E_ * E_;           // [M,3E] (V region unused)
    unsigned short* att_bf = qkv_bf + (size_t)M * E3;         // [M,E]
    unsigned short* vt_bf  = att_bf + (size_t)M * E_;         // [B*H*64,1024]

    prep_kernel<<<NCVT + NTA + NTP, 256, 0, stream>>>(x, x_bf, w_attn, wat, w_proj, wpt);

    // QKV: 128x128 tiles (measured best), grid 18 x 64
    gemm_mfma_kernel<unsigned short, 1, 128, 128, 2, 2>
        <<<dim3(E3 / 128, M / 128), 256, 0, stream>>>(
        x_bf, wat, b_attn, qkv_bf, vt_bf, M, E3, E_);

    flash_attn_kernel<<<B_ * H_ * 8, 256, 0, stream>>>(qkv_bf, vt_bf, att_bf);

    // proj: 64x128 tiles -> 768 blocks
    gemm_mfma_kernel<float, 0, 64, 128, 2, 2>
        <<<dim3(E_ / 128, M / 64), 256, 0, stream>>>(
        att_bf, wpt, b_proj, out, nullptr, M, E_, E_);
}

// Round 10
// 199.686 us; speedup vs baseline: 1.0839x; 1.0084x over previous
//
#include <hip/hip_runtime.h>
#include <math.h>

// GPT attention block: B=8, T=1024, E=768, H=12, D=64. fp32 in/out.
// Round 10: flash computes S^T (mfma operand swap) -> P pack is 8 ds_write_b64
// per phase instead of 32 ds_write_u16 (LDS write pipe was oversubscribed);
// lsum becomes per-lane scalar with 2-shuffle final reduction.
// K/Q load addresses are unchanged by the swap (A and B frags share layout).
// GEMMs (QKV 128x128, proj 64x128), prep unchanged from round 9.

#define B_ 8
#define T_ 1024
#define E_ 768
#define H_ 12
#define D_ 64
#define E3 (3 * E_)

typedef __attribute__((ext_vector_type(8))) short bf16x8;
typedef __attribute__((ext_vector_type(4))) float f32x4;

#define SCALE 0.18033688f // 0.125 * log2(e)

__device__ __forceinline__ unsigned short f2bf(float f) {
    unsigned int u = __builtin_bit_cast(unsigned int, f);
    u += 0x7fffu + ((u >> 16) & 1u);   // RNE
    return (unsigned short)(u >> 16);
}

__device__ __forceinline__ void async_copy16(void* lds, const void* g) {
    __builtin_amdgcn_global_load_lds(
        (const __attribute__((address_space(1))) void*)g,
        (__attribute__((address_space(3))) void*)lds, 16, 0, 0);
}

// ---------------- fused prep: x->bf16, w_attn^T, w_proj^T ----------------
#define NCVT 6144                 // (8192*768/4)/256
#define NTA  (72 * 24)            // (E3/32) x (E_/32)
#define NTP  (24 * 24)            // (E_/32) x (E_/32)

__device__ __forceinline__ void transpose_tile(
    const float* __restrict__ W, unsigned short* __restrict__ Wt,
    int K, int N, int gx, int gy, unsigned short (*tile)[33])
{
    const int n0 = gx * 32, k0 = gy * 32;
    const int tx = threadIdx.x & 31, ty = threadIdx.x >> 5;
    #pragma unroll
    for (int i = 0; i < 4; ++i)
        tile[ty + i * 8][tx] = f2bf(W[(size_t)(k0 + ty + i * 8) * N + n0 + tx]);
    __syncthreads();
    #pragma unroll
    for (int i = 0; i < 4; ++i)
        Wt[(size_t)(n0 + ty + i * 8) * K + k0 + tx] = tile[tx][ty + i * 8];
}

__global__ __launch_bounds__(256) void prep_kernel(
    const float* __restrict__ x, unsigned short* __restrict__ x_bf,
    const float* __restrict__ w_attn, unsigned short* __restrict__ wat,
    const float* __restrict__ w_proj, unsigned short* __restrict__ wpt)
{
    __shared__ unsigned short tile[32][33];
    const int bid = blockIdx.x;
    if (bid < NCVT) {
        const int i = bid * 256 + threadIdx.x;
        float4 f = ((const float4*)x)[i];
        ushort4 o;
        o.x = f2bf(f.x); o.y = f2bf(f.y); o.z = f2bf(f.z); o.w = f2bf(f.w);
        ((ushort4*)x_bf)[i] = o;
    } else if (bid < NCVT + NTA) {
        const int t = bid - NCVT;
        transpose_tile(w_attn, wat, E_, E3, t % 72, t / 72, tile);
    } else {
        const int t = bid - NCVT - NTA;
        transpose_tile(w_proj, wpt, E_, E_, t % 24, t / 24, tile);
    }
}

// ---------------- bf16 MFMA GEMM (unchanged) ----------------
template <typename OutT, int MODE, int BM, int BN, int WR, int WC>
__global__ __launch_bounds__(256) void gemm_mfma_kernel(
    const unsigned short* __restrict__ A,   // [M,K] bf16
    const unsigned short* __restrict__ Wt,  // [N,K] bf16
    const float* __restrict__ bias,
    OutT* __restrict__ C,
    unsigned short* __restrict__ vt,        // MODE 1 only
    int M, int N, int K)
{
    constexpr int MT = BM / WR / 16;
    constexpr int NT = BN / WC / 16;
    constexpr int CA = BM / 32;
    constexpr int CB = BN / 32;
    constexpr int QBX = 768 / BN;
    constexpr int VBX = 1536 / BN;

    __shared__ unsigned short Abuf[BM * 64];
    __shared__ unsigned short Bbuf[BN * 64];

    const int tid = threadIdx.x;
    const int lane = tid & 63;
    const int w = tid >> 6;
    const int n16 = lane & 15;
    const int quad = lane >> 4;

    const int nbx = gridDim.x;
    const int lin = blockIdx.y * nbx + blockIdx.x;
    const int band_sz = 8 * nbx;
    const int band = lin / band_sz;
    const int rr = lin % band_sz;
    const int bm = (band * 8 + (rr & 7)) * BM;
    const int bx = rr >> 3;
    const int bn = bx * BN;

    const int wmbase = (w / WC) * (BM / WR);
    const int wnbase = (w % WC) * (BN / WC);

    const int lrow = lane >> 3;
    const int lcol = ((lane & 7) ^ lrow) * 8;

    f32x4 acc[MT][NT] = {};

    for (int k0 = 0; k0 < K; k0 += 64) {
        __syncthreads();
        #pragma unroll
        for (int i = 0; i < CA; ++i) {
            const int c = w * CA + i;
            const int row = c * 8 + lrow;
            async_copy16(&Abuf[c * 512], A + (size_t)(bm + row) * K + k0 + lcol);
        }
        #pragma unroll
        for (int i = 0; i < CB; ++i) {
            const int c = w * CB + i;
            const int row = c * 8 + lrow;
            async_copy16(&Bbuf[c * 512], Wt + (size_t)(bn + row) * K + k0 + lcol);
        }
        __syncthreads();

        #pragma unroll
        for (int kc = 0; kc < 2; ++kc) {
            bf16x8 af[MT], bf[NT];
            #pragma unroll
            for (int mt = 0; mt < MT; ++mt) {
                const int r = wmbase + mt * 16 + n16;
                af[mt] = *(const bf16x8*)&Abuf[r * 64 + ((kc * 4 + quad) ^ (r & 7)) * 8];
            }
            #pragma unroll
            for (int nt = 0; nt < NT; ++nt) {
                const int r = wnbase + nt * 16 + n16;
                bf[nt] = *(const bf16x8*)&Bbuf[r * 64 + ((kc * 4 + quad) ^ (r & 7)) * 8];
            }
            #pragma unroll
            for (int mt = 0; mt < MT; ++mt)
                #pragma unroll
                for (int nt = 0; nt < NT; ++nt)
                    acc[mt][nt] = __builtin_amdgcn_mfma_f32_16x16x32_bf16(
                        af[mt], bf[nt], acc[mt][nt], 0, 0, 0);
        }
    }

    if (MODE == 1 && bx >= VBX) {
        #pragma unroll
        for (int mt = 0; mt < MT; ++mt) {
            const int tt = bm + wmbase + mt * 16 + quad * 4;
            const size_t bb = (size_t)(tt >> 10) * 768;
            const int tin = tt & 1023;
            #pragma unroll
            for (int nt = 0; nt < NT; ++nt) {
                const int col = bn + wnbase + nt * 16 + n16;
                const int ch = col - 1536;
                const float bv = bias[col];
                ushort4 o4;
                o4.x = f2bf(acc[mt][nt][0] + bv);
                o4.y = f2bf(acc[mt][nt][1] + bv);
                o4.z = f2bf(acc[mt][nt][2] + bv);
                o4.w = f2bf(acc[mt][nt][3] + bv);
                *(ushort4*)&vt[(bb + ch) * 1024 + tin] = o4;
            }
        }
        return;
    }

    const bool scale_q = (MODE == 1) && (bx < QBX);
    #pragma unroll
    for (int mt = 0; mt < MT; ++mt) {
        #pragma unroll
        for (int r = 0; r < 4; ++r) {
            const size_t rowoff = (size_t)(bm + wmbase + mt * 16 + quad * 4 + r) * N;
            #pragma unroll
            for (int nt = 0; nt < NT; ++nt) {
                const int col = bn + wnbase + nt * 16 + n16;
                float v = acc[mt][nt][r] + bias[col];
                if (scale_q) v *= SCALE;
                if constexpr (sizeof(OutT) == 2) C[rowoff + col] = (OutT)f2bf(v);
                else                             C[rowoff + col] = (OutT)v;
            }
        }
    }
}

// ---------------- Flash attention v5: S^T + merged paired q-tiles ----------------
#define BKEY 128
#define VSTR 136

__global__ __launch_bounds__(256) void flash_attn_kernel(
    const unsigned short* __restrict__ qkv,
    const unsigned short* __restrict__ vt,   // [(b*H+h)*64+d][1024] bf16
    unsigned short* __restrict__ out)
{
    __shared__ unsigned short Ks[BKEY * 64];
    __shared__ unsigned short Vts[64 * BKEY];
    __shared__ unsigned short Ps[4 * 16 * VSTR];

    const int tid = threadIdx.x;
    const int idx = blockIdx.x;
    const int head = idx % 96;
    const int p    = idx / 96;          // 0..7
    const int h = head % H_;
    const int b = head / H_;

    const int lane = tid & 63;
    const int w    = tid >> 6;
    const int n16  = lane & 15;
    const int quad = lane >> 4;

    const size_t base = (size_t)b * T_ * E3;
    const unsigned short* qbase = qkv + base + h * D_;          // pre-scaled q
    const unsigned short* kbase = qkv + base + E_ + h * D_;
    const unsigned short* vtb   = vt + (size_t)(b * H_ + h) * 64 * 1024;

    const int lrow = lane >> 3;
    const int lcol = ((lane & 7) ^ lrow) * 8;
    const int vr4 = lane >> 4;
    const int vc  = lane & 15;

    unsigned short* pw = &Ps[w * 16 * VSTR];

    const int qtA = p, qtB = 15 - p;
    const int nIterA = (qtA + 2) >> 1;
    const int nIterB = (qtB + 2) >> 1;
    const int wqA = qtA * 64 + w * 16;
    const int wqB = qtB * 64 + w * 16;

    const unsigned short* qrpA = qbase + (size_t)(wqA + n16) * E3 + quad * 8;
    bf16x8 qfA0 = *(const bf16x8*)qrpA;
    bf16x8 qfA1 = *(const bf16x8*)(qrpA + 32);
    const unsigned short* qrpB = qbase + (size_t)(wqB + n16) * E3 + quad * 8;
    bf16x8 qfB0 = *(const bf16x8*)qrpB;
    bf16x8 qfB1 = *(const bf16x8*)(qrpB + 32);

    f32x4 oA[4] = {}, oB[4] = {};
    float lsA = 0.f, lsB = 0.f;

    for (int it = 0; it < nIterB; ++it) {
        const int k0 = it * BKEY;
        __syncthreads();

        // ---- stage K [key][dim], XOR-swizzled, async ----
        #pragma unroll
        for (int i = 0; i < 4; ++i) {
            const int c = w * 4 + i;
            const int row = c * 8 + lrow;
            async_copy16(&Ks[c * 512], kbase + (size_t)(k0 + row) * E3 + lcol);
        }
        // ---- stage V^T [dim][key] from vt, XOR key-group swizzle, async ----
        #pragma unroll
        for (int i = 0; i < 4; ++i) {
            const int j = w * 4 + i;
            const int row = 4 * j + vr4;
            async_copy16(&Vts[4 * j * BKEY],
                         vtb + (size_t)row * 1024 + k0 + ((vc ^ (row & 15)) * 8));
        }
        __syncthreads();

        // phase computes S^T: mfma(A=K, B=Q) -> rows = keys, cols = q.
        // Lane holds S^T[key = knt*16 + quad*4 + r][q = wave_q_min + n16].
        auto phase = [&](bf16x8 qf0, bf16x8 qf1, f32x4* o, float& lsum,
                         int wave_q_min) {
            int knt_lim = ((wave_q_min + 15 - k0) >> 4) + 1;
            if (knt_lim > 8) knt_lim = 8;
            const int ks_lim = (knt_lim + 1) >> 1;
            int Ab2 = wave_q_min - k0 - 15;
            int kfull = Ab2 < 0 ? 0 : (Ab2 >> 4) + 1;
            if (kfull > 8) kfull = 8;

            const int qcol = wave_q_min + n16;           // this lane's q row

            f32x4 s[8];
            #pragma unroll
            for (int knt = 0; knt < 8; ++knt) {
                if (knt < knt_lim) {
                    const int r = knt * 16 + n16;
                    bf16x8 kf0 = *(const bf16x8*)&Ks[r * 64 + ((0 + quad) ^ (r & 7)) * 8];
                    bf16x8 kf1 = *(const bf16x8*)&Ks[r * 64 + ((4 + quad) ^ (r & 7)) * 8];
                    f32x4 acc = {0.f, 0.f, 0.f, 0.f};
                    acc = __builtin_amdgcn_mfma_f32_16x16x32_bf16(kf0, qf0, acc, 0, 0, 0);
                    acc = __builtin_amdgcn_mfma_f32_16x16x32_bf16(kf1, qf1, acc, 0, 0, 0);
                    s[knt] = acc;
                }
            }
            // causal mask: key row (k0+knt*16+quad*4+r) > qcol -> -inf
            #pragma unroll
            for (int knt = 0; knt < 8; ++knt) {
                if (knt >= kfull) {
                    const int krow = k0 + knt * 16 + quad * 4;
                    #pragma unroll
                    for (int r = 0; r < 4; ++r) {
                        float v = (knt < knt_lim) ? s[knt][r] : -1e30f;
                        if (krow + r > qcol) v = -1e30f;
                        s[knt][r] = v;
                    }
                }
            }

            // exp2, lsum (per-lane scalar), pack P[q][key]: 4 consecutive keys
            // per lane per knt -> one b64 store.
            #pragma unroll
            for (int knt = 0; knt < 8; ++knt) {
                float pv0 = __builtin_amdgcn_exp2f(s[knt][0]);
                float pv1 = __builtin_amdgcn_exp2f(s[knt][1]);
                float pv2 = __builtin_amdgcn_exp2f(s[knt][2]);
                float pv3 = __builtin_amdgcn_exp2f(s[knt][3]);
                lsum += (pv0 + pv1) + (pv2 + pv3);
                unsigned int u0 = __builtin_bit_cast(unsigned int, pv0);
                unsigned int u1 = __builtin_bit_cast(unsigned int, pv1);
                unsigned int u2 = __builtin_bit_cast(unsigned int, pv2);
                unsigned int u3 = __builtin_bit_cast(unsigned int, pv3);
                uint2 pk;
                pk.x = ((u0 + 0x8000u) >> 16) | ((u1 + 0x8000u) & 0xffff0000u);
                pk.y = ((u2 + 0x8000u) >> 16) | ((u3 + 0x8000u) & 0xffff0000u);
                *(uint2*)&pw[n16 * VSTR + knt * 16 + quad * 4] = pk;
            }

            // ---- O += P V ----
            #pragma unroll
            for (int ks = 0; ks < 4; ++ks) {
                if (ks < ks_lim) {
                    bf16x8 pf = *(const bf16x8*)&pw[n16 * VSTR + ks * 32 + quad * 8];
                    #pragma unroll
                    for (int dt = 0; dt < 4; ++dt) {
                        const int row = dt * 16 + n16;
                        bf16x8 vf = *(const bf16x8*)&Vts[row * BKEY +
                                        (((ks * 4 + quad) ^ n16) * 8)];
                        o[dt] = __builtin_amdgcn_mfma_f32_16x16x32_bf16(pf, vf, o[dt], 0, 0, 0);
                    }
                }
            }
        };

        phase(qfB0, qfB1, oB, lsB, wqB);
        if (it < nIterA) phase(qfA0, qfA1, oA, lsA, wqA);
    }

    // ---- final l reduction: lanes sharing n16 hold partials for q=n16 ----
    lsA += __shfl_xor(lsA, 16); lsA += __shfl_xor(lsA, 32);
    lsB += __shfl_xor(lsB, 16); lsB += __shfl_xor(lsB, 32);
    // now lane L holds total for local q-index L&15

    #pragma unroll
    for (int r = 0; r < 4; ++r) {
        const float invA = 1.f / __shfl(lsA, quad * 4 + r);
        unsigned short* orowA = out + ((size_t)b * T_ + wqA + quad * 4 + r) * E_ + h * D_;
        #pragma unroll
        for (int dt = 0; dt < 4; ++dt)
            orowA[dt * 16 + n16] = f2bf(oA[dt][r] * invA);
        const float invB = 1.f / __shfl(lsB, quad * 4 + r);
        unsigned short* orowB = out + ((size_t)b * T_ + wqB + quad * 4 + r) * E_ + h * D_;
        #pragma unroll
        for (int dt = 0; dt < 4; ++dt)
            orowB[dt * 16 + n16] = f2bf(oB[dt][r] * invB);
    }
}

extern "C" void kernel_launch(void* const* d_in, const int* in_sizes, int n_in,
                              void* d_out, int out_size, void* d_ws, size_t ws_size,
                              hipStream_t stream)
{
    const float* x      = (const float*)d_in[0];
    const float* w_attn = (const float*)d_in[1];
    const float* b_attn = (const float*)d_in[2];
    const float* w_proj = (const float*)d_in[3];
    const float* b_proj = (const float*)d_in[4];
    float* out = (float*)d_out;

    const int M = B_ * T_;  // 8192

    unsigned short* x_bf   = (unsigned short*)d_ws;           // [M,E]
    unsigned short* wat    = x_bf + (size_t)M * E_;           // [3E,E]
    unsigned short* wpt    = wat + (size_t)E3 * E_;           // [E,E]
    unsigned short* qkv_bf = wpt + (size_t)E_ * E_;           // [M,3E] (V region unused)
    unsigned short* att_bf = qkv_bf + (size_t)M * E3;         // [M,E]
    unsigned short* vt_bf  = att_bf + (size_t)M * E_;         // [B*H*64,1024]

    prep_kernel<<<NCVT + NTA + NTP, 256, 0, stream>>>(x, x_bf, w_attn, wat, w_proj, wpt);

    gemm_mfma_kernel<unsigned short, 1, 128, 128, 2, 2>
        <<<dim3(E3 / 128, M / 128), 256, 0, stream>>>(
        x_bf, wat, b_attn, qkv_bf, vt_bf, M, E3, E_);

    flash_attn_kernel<<<B_ * H_ * 8, 256, 0, stream>>>(qkv_bf, vt_bf, att_bf);

    gemm_mfma_kernel<float, 0, 64, 128, 2, 2>
        <<<dim3(E_ / 128, M / 64), 256, 0, stream>>>(
        att_bf, wpt, b_proj, out, nullptr, M, E_, E_);
}